// Round 12
// baseline (299.944 us; speedup 1.0000x reference)
//
#include <hip/hip_runtime.h>
#include <hip/hip_bf16.h>

#define TB 16384
#define CDIM 512
#define OUTD 512
#define NE 16
#define NE_TOT 17
#define LOSS_SCALE 0.01f
#define BM 256
#define BN 128
#define BK 32
#define NSTEP 16
#define MAX_SCHED 80
#define MAXFLAG 8192
#define MARGIN 1e-3f

typedef __bf16 bf16_t;
typedef bf16_t bf16x8 __attribute__((ext_vector_type(8)));
typedef float f32x4 __attribute__((ext_vector_type(4)));
typedef unsigned short ushort4_t __attribute__((ext_vector_type(4)));
typedef unsigned short ushort8_t __attribute__((ext_vector_type(8)));

__device__ __forceinline__ unsigned short f2bf(float f) {
    unsigned int u = __float_as_uint(f);
    u += 0x7fffu + ((u >> 16) & 1u);   // round-to-nearest-even
    return (unsigned short)(u >> 16);
}
__device__ __forceinline__ float bf2f(unsigned short h) {
    return __uint_as_float((unsigned int)h << 16);
}
// 4-chunk swizzle within a 64B K-tile; depends only on row&15
__device__ __forceinline__ int sw4(int r) { return (r ^ (r >> 2)) & 3; }

__device__ __forceinline__ void async_copy16(void* lds, const void* g) {
    __builtin_amdgcn_global_load_lds(
        (const __attribute__((address_space(1))) unsigned int*)g,
        (__attribute__((address_space(3))) unsigned int*)lds, 16, 0, 0);
}

// ---------------- prep: init small state + assign_w hi/lo bf16 split ----------------
__global__ __launch_bounds__(256) void k_prep(
    const float* __restrict__ aw, unsigned short* __restrict__ awhl,
    int* cnt0, int* cnt1, float* importance, int* nflag, int* wflag, int* done0)
{
    int t = threadIdx.x;
    if (t < NE) { cnt0[t] = 0; cnt1[t] = 0; importance[t] = 0.f; }
    if (t == 0) { *nflag = 0; *wflag = 0; *done0 = 0; }
    for (int i = t; i < NE * CDIM; i += 256) {
        float f = aw[i];
        unsigned short h = f2bf(f);
        float r = f - bf2f(h);
        awhl[i] = h;
        awhl[NE * CDIM + i] = f2bf(r);
    }
}

// pw_w1 + bias_w -> wbf [17][OUT][C] bf16 with baked 4-chunk swizzle
// (16B-chunk cc' = cc ^ sw4(row&15) within each 64B K-tile) + wflag detect.
__global__ void k_wconv(const float* __restrict__ pw, const float* __restrict__ bw,
                        unsigned short* __restrict__ wbf, int* __restrict__ wflag) {
    long i = (long)blockIdx.x * 256 + threadIdx.x;   // float4 index
    const long NPW = (long)NE * OUTD * CDIM / 4;
    const long NTOT = (long)NE_TOT * OUTD * CDIM / 4;
    if (i >= NTOT) return;
    const float* src = (i < NPW) ? (pw + i * 4) : (bw + (i - NPW) * 4);
    float4 v = *(const float4*)src;
    ushort4_t o;
    o[0] = f2bf(v.x); o[1] = f2bf(v.y); o[2] = f2bf(v.z); o[3] = f2bf(v.w);
    long row = i >> 7;                 // global row (e*512 + out_row)
    int e0 = (int)(i & 127) * 4;       // element offset in row
    int kt = e0 >> 5;                  // which 64B (32-elem) K-tile
    int cc = (e0 >> 3) & 3;            // 16B chunk within tile
    int half = e0 & 7;                 // 0 or 4
    int ccs = cc ^ sw4((int)(row & 15));
    *(ushort4_t*)(wbf + row * CDIM + kt * 32 + ccs * 8 + half) = o;
    if (i >= NPW && (v.x != 0.f || v.y != 0.f || v.z != 0.f || v.w != 0.f))
        atomicOr(wflag, 1);
}

// ---------------- gating via MFMA hi/lo (+ bf16 cache + per-rank counts) ----------------
__global__ __launch_bounds__(256) void k_gate(
    const float* __restrict__ x, const unsigned short* __restrict__ awhl,
    const float* __restrict__ ab, unsigned short* __restrict__ xbf,
    int* __restrict__ dec, float2* __restrict__ respd,
    int* __restrict__ flaglist, int* __restrict__ nflag, float* __restrict__ importance,
    int* __restrict__ cnt0, int* __restrict__ cnt1)
{
    __shared__ float imp_s[NE];
    __shared__ int c0_s[NE], c1_s[NE];
    int tid = threadIdx.x;
    if (tid < NE) { imp_s[tid] = 0.f; c0_s[tid] = 0; c1_s[tid] = 0; }
    __syncthreads();

    int wv = tid >> 6, l = tid & 63;
    int n0 = blockIdx.x * 64 + wv * 16;
    int e = l & 15;          // expert (B row); also A-load token row
    int kg = l >> 4;

    const float* xrow = x + (size_t)(n0 + e) * CDIM + kg * 8;
    unsigned short* xbrow = xbf + (size_t)(n0 + e) * CDIM + kg * 8;
    const unsigned short* whiP = awhl + e * CDIM + kg * 8;
    const unsigned short* wloP = whiP + NE * CDIM;

    f32x4 acc = (f32x4){0.f, 0.f, 0.f, 0.f};
    #pragma unroll 4
    for (int ks = 0; ks < 16; ++ks) {
        float4 v0 = *(const float4*)(xrow + ks * 32);
        float4 v1 = *(const float4*)(xrow + ks * 32 + 4);
        ushort8_t hx, lx;
        #define CVT(idx, f) { unsigned short h_ = f2bf(f); hx[idx] = h_; \
                              float r_ = (f) - bf2f(h_); lx[idx] = f2bf(r_); }
        CVT(0, v0.x) CVT(1, v0.y) CVT(2, v0.z) CVT(3, v0.w)
        CVT(4, v1.x) CVT(5, v1.y) CVT(6, v1.z) CVT(7, v1.w)
        #undef CVT
        *(ushort8_t*)(xbrow + ks * 32) = hx;
        ushort8_t wh8 = *(const ushort8_t*)(whiP + ks * 32);
        ushort8_t wl8 = *(const ushort8_t*)(wloP + ks * 32);
        bf16x8 ah = *(bf16x8*)&hx, al = *(bf16x8*)&lx;
        bf16x8 bh = *(bf16x8*)&wh8, bl = *(bf16x8*)&wl8;
        acc = __builtin_amdgcn_mfma_f32_16x16x32_bf16(al, bh, acc, 0, 0, 0);
        acc = __builtin_amdgcn_mfma_f32_16x16x32_bf16(ah, bl, acc, 0, 0, 0);
        acc = __builtin_amdgcn_mfma_f32_16x16x32_bf16(ah, bh, acc, 0, 0, 0);
    }
    float bias = ab[e];
    f32x4 E;
    #pragma unroll
    for (int q = 0; q < 4; ++q) E[q] = acc[q] + bias;

    f32x4 m1 = E, m2, m3;
    #pragma unroll
    for (int q = 0; q < 4; ++q) { m2[q] = -3.4e38f; m3[q] = -3.4e38f; }
    #pragma unroll
    for (int off = 1; off <= 8; off <<= 1) {
        #pragma unroll
        for (int q = 0; q < 4; ++q) {
            float o1 = __shfl_xor(m1[q], off, 64);
            float o2 = __shfl_xor(m2[q], off, 64);
            float o3 = __shfl_xor(m3[q], off, 64);
            float M1 = fmaxf(m1[q], o1), x1 = fminf(m1[q], o1);
            float h2 = fmaxf(m2[q], o2), l2 = fminf(m2[q], o2);
            float M2 = fmaxf(x1, h2), x2 = fminf(x1, h2);
            float M3 = fmaxf(fmaxf(x2, l2), fmaxf(m3[q], o3));
            m1[q] = M1; m2[q] = M2; m3[q] = M3;
        }
    }
    f32x4 p, z;
    #pragma unroll
    for (int q = 0; q < 4; ++q) p[q] = (E[q] >= m2[q]) ? expf(E[q] - m1[q]) : 0.f;
    z = p;
    #pragma unroll
    for (int off = 1; off <= 8; off <<= 1)
        #pragma unroll
        for (int q = 0; q < 4; ++q) z[q] += __shfl_xor(z[q], off, 64);
    f32x4 resp;
    #pragma unroll
    for (int q = 0; q < 4; ++q) resp[q] = p[q] / z[q];

    int grp = l >> 4;
    int elo_q[4], ehi_q[4];
    float rlo_q[4], rhi_q[4];
    #pragma unroll
    for (int q = 0; q < 4; ++q) {
        unsigned long long mq = __ballot(p[q] > 0.f);
        unsigned int sub = (unsigned int)((mq >> (grp * 16)) & 0xffffULL);
        elo_q[q] = __builtin_ctz(sub);
        ehi_q[q] = 31 - __builtin_clz(sub);
        rlo_q[q] = __shfl(resp[q], grp * 16 + elo_q[q], 64);
        rhi_q[q] = __shfl(resp[q], grp * 16 + ehi_q[q], 64);
    }
    if ((l & 15) == 0) {
        #pragma unroll
        for (int q = 0; q < 4; ++q) {
            int n = n0 + grp * 4 + q;
            dec[n] = elo_q[q] | (ehi_q[q] << 8);
            respd[n] = make_float2(rlo_q[q], rhi_q[q]);
            atomicAdd(&c0_s[elo_q[q]], 1);
            atomicAdd(&c1_s[ehi_q[q]], 1);
            if (m2[q] - m3[q] < MARGIN) {
                int ix = atomicAdd(nflag, 1);
                if (ix < MAXFLAG) flaglist[ix] = n;
            }
        }
    }
    float s = resp[0] + resp[1] + resp[2] + resp[3];
    s += __shfl_xor(s, 16, 64);
    s += __shfl_xor(s, 32, 64);
    if (l < 16) atomicAdd(&imp_s[e], s);
    __syncthreads();
    if (tid < NE) {
        unsafeAtomicAdd(&importance[tid], imp_s[tid]);
        if (c0_s[tid]) atomicAdd(&cnt0[tid], c0_s[tid]);
        if (c1_s[tid]) atomicAdd(&cnt1[tid], c1_s[tid]);
    }
}

// ---------------- fp64 repair for ambiguous tokens (also fixes counts) ----------------
__global__ __launch_bounds__(256) void k_repair(
    const float* __restrict__ x, const float* __restrict__ aw, const float* __restrict__ ab,
    const int* __restrict__ flaglist, const int* __restrict__ nflag,
    int* __restrict__ dec, float2* __restrict__ respd, float* __restrict__ importance,
    int* __restrict__ cnt0, int* __restrict__ cnt1)
{
    __shared__ double part[16][17];
    __shared__ double Ed[16];
    int tid = threadIdx.x;
    int e = tid >> 4, p = tid & 15;
    int nf = *nflag; if (nf > MAXFLAG) nf = MAXFLAG;
    for (int fi = blockIdx.x; fi < nf; fi += gridDim.x) {
        int n = flaglist[fi];
        const float* xp_ = x + (size_t)n * CDIM + p * 32;
        const float* wp = aw + e * CDIM + p * 32;
        double acc = 0.0;
        for (int j = 0; j < 32; ++j) acc = fma((double)xp_[j], (double)wp[j], acc);
        part[e][p] = acc;
        __syncthreads();
        if (tid < 16) {
            double s = (double)ab[tid];
            for (int q = 0; q < 16; ++q) s += part[tid][q];
            Ed[tid] = s;
        }
        __syncthreads();
        if (tid == 0) {
            double m1 = -1e300, m2 = -1e300, m3 = -1e300;
            for (int q = 0; q < 16; ++q) {
                double v = Ed[q];
                if (v > m1) { m3 = m2; m2 = m1; m1 = v; }
                else if (v > m2) { m3 = m2; m2 = v; }
                else if (v > m3) { m3 = v; }
            }
            int elo = -1, ehi = -1;
            for (int q = 0; q < 16; ++q)
                if (Ed[q] >= m2) { if (elo < 0) elo = q; else ehi = q; }
            double plo = exp(Ed[elo] - m1), phi = exp(Ed[ehi] - m1);
            double zz = plo + phi;
            float rlo = (float)(plo / zz), rhi = (float)(phi / zz);
            int od = dec[n]; float2 orr = respd[n];
            int oelo = od & 0xff, oehi = (od >> 8) & 0xff;
            unsafeAtomicAdd(&importance[oelo], -orr.x);
            unsafeAtomicAdd(&importance[oehi], -orr.y);
            unsafeAtomicAdd(&importance[elo], rlo);
            unsafeAtomicAdd(&importance[ehi], rhi);
            if (oelo != elo) { atomicSub(&cnt0[oelo], 1); atomicAdd(&cnt0[elo], 1); }
            if (oehi != ehi) { atomicSub(&cnt1[oehi], 1); atomicAdd(&cnt1[ehi], 1); }
            dec[n] = elo | (ehi << 8);
            respd[n] = make_float2(rlo, rhi);
        }
        __syncthreads();
    }
}

// ---------------- loss + prefix bases + schedules (BM=256 tiles) ----------------
__global__ void k_finish(const float* __restrict__ importance, float* __restrict__ out_loss,
                         const int* __restrict__ cnt0, const int* __restrict__ cnt1,
                         int* __restrict__ fill0, int* __restrict__ fill1,
                         int* __restrict__ end0a, int* __restrict__ end1a,
                         int* __restrict__ sched0, int* __restrict__ sched1,
                         int* __restrict__ sn0, int* __restrict__ sn1) {
    int l = threadIdx.x;
    if (l < 64) {
        float v = (l < NE) ? importance[l] : 0.f;
        float s = v;
        #pragma unroll
        for (int off = 8; off >= 1; off >>= 1) s += __shfl_xor(s, off, 64);
        float mean = s / 16.f;
        float d = (l < NE) ? (v - mean) : 0.f;
        float ss = d * d;
        #pragma unroll
        for (int off = 8; off >= 1; off >>= 1) ss += __shfl_xor(ss, off, 64);
        if (l == 0) {
            float stdv = sqrtf(ss / 15.f);   // ddof=1
            out_loss[0] = LOSS_SCALE * stdv / mean;
        }
    } else if (l == 64) {
        int p = 0, base = 0;
        for (int e = 0; e < NE; ++e) {
            fill0[e] = base;
            end0a[e] = base + cnt0[e];
            int nb = (cnt0[e] + BM - 1) / BM;
            for (int i = 0; i < nb; ++i) sched0[p++] = (e << 20) | (base + i * BM);
            base += cnt0[e];
        }
        *sn0 = p;
    } else if (l == 65) {
        int p = 0, base = 0;
        for (int e = 0; e < NE; ++e) {
            fill1[e] = base;
            end1a[e] = base + cnt1[e];
            int nb = (cnt1[e] + BM - 1) / BM;
            for (int i = 0; i < nb; ++i) sched1[p++] = (e << 20) | (base + i * BM);
            base += cnt1[e];
        }
        *sn1 = p;
    }
}

// ---------------- compacted scatter ----------------
__global__ __launch_bounds__(256) void k_scatter(
    const int* __restrict__ dec, int* __restrict__ fill0, int* __restrict__ fill1,
    int* __restrict__ idx0c, int* __restrict__ idx1c)
{
    __shared__ int l0[NE], l1[NE], b0[NE], b1[NE];
    int tid = threadIdx.x;
    if (tid < NE) { l0[tid] = 0; l1[tid] = 0; }
    __syncthreads();
    int n = blockIdx.x * 256 + tid;
    int d = dec[n];
    int elo = d & 0xff, ehi = (d >> 8) & 0xff;
    int p0 = atomicAdd(&l0[elo], 1);
    int p1 = atomicAdd(&l1[ehi], 1);
    __syncthreads();
    if (tid < NE) {
        b0[tid] = atomicAdd(&fill0[tid], l0[tid]);
        b1[tid] = atomicAdd(&fill1[tid], l1[tid]);
    }
    __syncthreads();
    idx0c[b0[elo] + p0] = n;
    idx1c[b1[ehi] + p1] = n;
}

// ---------------- merged MoE GEMM: rank0 + rank1 in ONE launch ----------------
// Exact R10 loop (2 LDS buffers, 2 barriers/K-step, counted vmcnt(3)).
// grid = (2*MAX_SCHED, 4); rank = blockIdx.x & 1, sched idx = blockIdx.x >> 1.
// gridDim.x % 8 == 0 keeps the 4 n-blocks of a tile on one XCD.
// Ordering: rank0 epilogue plain-stores y = w*acc + bias_b, threadfence,
// RELEASE-increments done0 (agent scope). rank1 computes, then lane0
// ACQUIRE-spins until done0 == *sn0 * 4, then RMWs y += w*acc.
// Deadlock-free: ≤320 rank1 blocks < 512 residency slots -> rank0 always runs.
__global__ __launch_bounds__(512) void k_moe(
    const unsigned short* __restrict__ xbf, const unsigned short* __restrict__ wbf,
    const int* __restrict__ idx0c, const int* __restrict__ idx1c,
    const float2* __restrict__ respd,
    const int* __restrict__ sched0, const int* __restrict__ sched1,
    const int* __restrict__ sn0, const int* __restrict__ sn1,
    const int* __restrict__ end0a, const int* __restrict__ end1a,
    const float* __restrict__ bias_b, float* __restrict__ y, int* __restrict__ done0)
{
    int rank = blockIdx.x & 1;
    int six = blockIdx.x >> 1;
    const int* sched = rank ? sched1 : sched0;
    const int* idxc  = rank ? idx1c  : idx0c;
    const int* enda  = rank ? end1a  : end0a;
    int sn = rank ? *sn1 : *sn0;
    if (six >= sn) return;
    int s = sched[six];
    int e = s >> 20, m0 = s & 0xFFFFF, end = enda[e];
    int n0 = blockIdx.y * BN;
    int tid = threadIdx.x;
    int wave = tid >> 6, lane = tid & 63;
    int wm = wave >> 1, wn = wave & 1;
    int fr = lane & 15, fq = lane >> 4;

    __shared__ unsigned short As[2][BM * BK];   // 32 KiB
    __shared__ unsigned short Bs[2][BN * BK];   // 16 KiB

    f32x4 acc[4][4];
    #pragma unroll
    for (int m = 0; m < 4; ++m)
        #pragma unroll
        for (int nn = 0; nn < 4; ++nn) acc[m][nn] = (f32x4){0.f, 0.f, 0.f, 0.f};

    // staging: 3 gload_lds per wave per K-tile (A:2, B:1), each = 16 rows x 64B.
    // lane l -> row l>>2, chunk l&3; A src gathered per-lane + XOR-swizzled chunk
    // (rule #21: linear LDS dest + swizzled source = swizzled read); B baked.
    int rl = lane >> 2, cc = lane & 3;
    const unsigned short* aS[2];
    #pragma unroll
    for (int c = 0; c < 2; ++c) {
        int rloc = wave * 32 + c * 16 + rl;
        int rr = m0 + rloc; if (rr >= end) rr = end - 1;
        aS[c] = xbf + (size_t)idxc[rr] * CDIM + (cc ^ sw4(rloc)) * 8;
    }
    const unsigned short* bS =
        wbf + ((size_t)e * OUTD + n0 + wave * 16 + rl) * CDIM + cc * 8;

    auto stage = [&](int buf, int t) {
        async_copy16(&As[buf][(wave * 32) * BK], aS[0] + t * BK);
        async_copy16(&As[buf][(wave * 32 + 16) * BK], aS[1] + t * BK);
        async_copy16(&Bs[buf][(wave * 16) * BK], bS + t * BK);
    };
    auto compute = [&](int cb) {
        bf16x8 af[4], bv[4];
        #pragma unroll
        for (int m = 0; m < 4; ++m) {
            int row = wm * 64 + m * 16 + fr;
            af[m] = *(const bf16x8*)(&As[cb][row * BK + ((fq ^ sw4(fr)) * 8)]);
        }
        #pragma unroll
        for (int nn = 0; nn < 4; ++nn) {
            int row = wn * 64 + nn * 16 + fr;
            bv[nn] = *(const bf16x8*)(&Bs[cb][row * BK + ((fq ^ sw4(fr)) * 8)]);
        }
        #pragma unroll
        for (int m = 0; m < 4; ++m)
            #pragma unroll
            for (int nn = 0; nn < 4; ++nn)
                acc[m][nn] = __builtin_amdgcn_mfma_f32_16x16x32_bf16(af[m], bv[nn], acc[m][nn], 0, 0, 0);
    };

    stage(0, 0); stage(1, 1);              // 2 K-tiles in flight (6 ops/wave)
    #pragma unroll
    for (int t = 0; t < NSTEP; ++t) {
        // T4: counted wait — tile t's 3 ops done, tile t+1's 3 stay in flight.
        if (t < NSTEP - 1) asm volatile("s_waitcnt vmcnt(3)" ::: "memory");
        else               asm volatile("s_waitcnt vmcnt(0)" ::: "memory");
        __builtin_amdgcn_sched_barrier(0);
        __builtin_amdgcn_s_barrier();      // all waves' tile-t loads landed
        asm volatile("" ::: "memory");
        compute(t & 1);
        __builtin_amdgcn_s_barrier();      // all waves done reading buf t&1
        asm volatile("" ::: "memory");
        if (t + 2 < NSTEP) stage(t & 1, t + 2);
    }

    if (rank == 0) {
        float bb[4];
        #pragma unroll
        for (int nn = 0; nn < 4; ++nn) bb[nn] = bias_b[n0 + wn * 64 + nn * 16 + fr];
        #pragma unroll
        for (int m = 0; m < 4; ++m)
            #pragma unroll
            for (int q = 0; q < 4; ++q) {
                int r = m0 + wm * 64 + m * 16 + fq * 4 + q;
                if (r < end) {
                    int tok = idxc[r];
                    float w = respd[tok].x;
                    float* yrow = y + (size_t)tok * OUTD + n0 + wn * 64 + fr;
                    #pragma unroll
                    for (int nn = 0; nn < 4; ++nn)
                        yrow[nn * 16] = fmaf(w, acc[m][nn][q], bb[nn]);
                }
            }
        __threadfence();                   // device-scope: publish stores
        __syncthreads();
        if (tid == 0)
            __hip_atomic_fetch_add(done0, 1, __ATOMIC_RELEASE, __HIP_MEMORY_SCOPE_AGENT);
    } else {
        if (tid == 0) {
            int need = *sn0 * 4;           // all rank0 blocks (4 n-blocks each)
            while (__hip_atomic_load(done0, __ATOMIC_ACQUIRE, __HIP_MEMORY_SCOPE_AGENT) < need)
                __builtin_amdgcn_s_sleep(8);
        }
        __syncthreads();
        #pragma unroll
        for (int m = 0; m < 4; ++m)
            #pragma unroll
            for (int q = 0; q < 4; ++q) {
                int r = m0 + wm * 64 + m * 16 + fq * 4 + q;
                if (r < end) {
                    int tok = idxc[r];
                    float w = respd[tok].y;
                    float* yrow = y + (size_t)tok * OUTD + n0 + wn * 64 + fr;
                    #pragma unroll
                    for (int nn = 0; nn < 4; ++nn)
                        yrow[nn * 16] += w * acc[m][nn][q];
                }
            }
    }
}

// ---------------- dense bias expert (y += x @ bias_w^T), wflag-gated ----------------
__global__ __launch_bounds__(512) void k_dense(
    const unsigned short* __restrict__ xbf, const unsigned short* __restrict__ wbf,
    const int* __restrict__ wflag, float* __restrict__ y)
{
    if (*wflag == 0) return;
    int e = NE;
    int m0 = blockIdx.x * BM;
    int n0 = blockIdx.y * BN;
    int tid = threadIdx.x;
    int wave = tid >> 6, lane = tid & 63;
    int wm = wave >> 1, wn = wave & 1;
    int fr = lane & 15, fq = lane >> 4;

    __shared__ unsigned short As[2][BM * BK];
    __shared__ unsigned short Bs[2][BN * BK];

    f32x4 acc[4][4];
    #pragma unroll
    for (int m = 0; m < 4; ++m)
        #pragma unroll
        for (int nn = 0; nn < 4; ++nn) acc[m][nn] = (f32x4){0.f, 0.f, 0.f, 0.f};

    int rl = lane >> 2, cc = lane & 3;
    const unsigned short* aS[2];
    #pragma unroll
    for (int c = 0; c < 2; ++c) {
        int rloc = wave * 32 + c * 16 + rl;
        aS[c] = xbf + (size_t)(m0 + rloc) * CDIM + (cc ^ sw4(rloc)) * 8;
    }
    const unsigned short* bS =
        wbf + ((size_t)e * OUTD + n0 + wave * 16 + rl) * CDIM + cc * 8;

    auto stage = [&](int buf, int t) {
        async_copy16(&As[buf][(wave * 32) * BK], aS[0] + t * BK);
        async_copy16(&As[buf][(wave * 32 + 16) * BK], aS[1] + t * BK);
        async_copy16(&Bs[buf][(wave * 16) * BK], bS + t * BK);
    };
    auto compute = [&](int cb) {
        bf16x8 af[4], bv[4];
        #pragma unroll
        for (int m = 0; m < 4; ++m) {
            int row = wm * 64 + m * 16 + fr;
            af[m] = *(const bf16x8*)(&As[cb][row * BK + ((fq ^ sw4(fr)) * 8)]);
        }
        #pragma unroll
        for (int nn = 0; nn < 4; ++nn) {
            int row = wn * 64 + nn * 16 + fr;
            bv[nn] = *(const bf16x8*)(&Bs[cb][row * BK + ((fq ^ sw4(fr)) * 8)]);
        }
        #pragma unroll
        for (int m = 0; m < 4; ++m)
            #pragma unroll
            for (int nn = 0; nn < 4; ++nn)
                acc[m][nn] = __builtin_amdgcn_mfma_f32_16x16x32_bf16(af[m], bv[nn], acc[m][nn], 0, 0, 0);
    };

    stage(0, 0); stage(1, 1);
    #pragma unroll
    for (int t = 0; t < NSTEP; ++t) {
        if (t < NSTEP - 1) asm volatile("s_waitcnt vmcnt(3)" ::: "memory");
        else               asm volatile("s_waitcnt vmcnt(0)" ::: "memory");
        __builtin_amdgcn_sched_barrier(0);
        __builtin_amdgcn_s_barrier();
        asm volatile("" ::: "memory");
        compute(t & 1);
        __builtin_amdgcn_s_barrier();
        asm volatile("" ::: "memory");
        if (t + 2 < NSTEP) stage(t & 1, t + 2);
    }

    #pragma unroll
    for (int m = 0; m < 4; ++m)
        #pragma unroll
        for (int q = 0; q < 4; ++q) {
            int r = m0 + wm * 64 + m * 16 + fq * 4 + q;
            float* yrow = y + (size_t)r * OUTD + n0 + wn * 64 + fr;
            #pragma unroll
            for (int nn = 0; nn < 4; ++nn) yrow[nn * 16] += acc[m][nn][q];
        }
}

extern "C" void kernel_launch(void* const* d_in, const int* in_sizes, int n_in,
                              void* d_out, int out_size, void* d_ws, size_t ws_size,
                              hipStream_t stream) {
    const float* x        = (const float*)d_in[0];
    const float* assign_w = (const float*)d_in[1];
    const float* assign_b = (const float*)d_in[2];
    const float* pw_w1    = (const float*)d_in[3];
    const float* bias_w   = (const float*)d_in[4];
    const float* bias_b   = (const float*)d_in[5];
    float* y    = (float*)d_out;                 // [TB*OUTD]
    float* loss = y + (size_t)TB * OUTD;         // [1]

    char* ws = (char*)d_ws;
    unsigned short* wbf  = (unsigned short*)(ws);                 //  8,912,896 B
    unsigned short* xbf  = (unsigned short*)(ws + 8912896);       // 16,777,216 B
    int*    idx0c     = (int*)   (ws + 25690112);                 //     65,536 B
    int*    idx1c     = (int*)   (ws + 25755648);                 //     65,536 B
    int*    dec       = (int*)   (ws + 25821184);                 //     65,536 B
    float2* respd     = (float2*)(ws + 25886720);                 //    131,072 B
    int*    flaglist  = (int*)   (ws + 26017792);                 //     32,768 B
    unsigned short* awhl = (unsigned short*)(ws + 26050560);      //     32,768 B
    char*   misc      = ws + 26083328;
    int*    cnt0      = (int*)   (misc + 0);
    int*    cnt1      = (int*)   (misc + 64);
    int*    fill0     = (int*)   (misc + 128);
    int*    fill1     = (int*)   (misc + 192);
    int*    end0a     = (int*)   (misc + 256);
    int*    end1a     = (int*)   (misc + 320);
    float*  importance= (float*) (misc + 384);
    int*    nflag     = (int*)   (misc + 448);
    int*    wflag     = (int*)   (misc + 452);
    int*    sn0       = (int*)   (misc + 456);
    int*    sn1       = (int*)   (misc + 460);
    int*    done0     = (int*)   (misc + 464);
    int*    sched0    = (int*)   (misc + 512);                    // 80*4
    int*    sched1    = (int*)   (misc + 832);                    // 80*4

    k_prep<<<1, 256, 0, stream>>>(assign_w, awhl, cnt0, cnt1, importance, nflag, wflag, done0);
    k_wconv<<<(NE_TOT * OUTD * CDIM / 4 + 255) / 256, 256, 0, stream>>>(pw_w1, bias_w, wbf, wflag);
    k_gate<<<TB / 64, 256, 0, stream>>>(x, awhl, assign_b, xbf, dec, respd,
                                        flaglist, nflag, importance, cnt0, cnt1);
    k_repair<<<32, 256, 0, stream>>>(x, assign_w, assign_b, flaglist, nflag,
                                     dec, respd, importance, cnt0, cnt1);
    k_finish<<<1, 128, 0, stream>>>(importance, loss, cnt0, cnt1, fill0, fill1,
                                    end0a, end1a, sched0, sched1, sn0, sn1);
    k_scatter<<<TB / 256, 256, 0, stream>>>(dec, fill0, fill1, idx0c, idx1c);
    k_moe<<<dim3(2 * MAX_SCHED, OUTD / BN), 512, 0, stream>>>(
        xbf, wbf, idx0c, idx1c, respd, sched0, sched1, sn0, sn1,
        end0a, end1a, bias_b, y, done0);
    k_dense<<<dim3(TB / BM, OUTD / BN), 512, 0, stream>>>(xbf, wbf, wflag, y);
}

// Round 13
// 106.491 us; speedup vs baseline: 2.8166x; 2.8166x over previous
//
#include <hip/hip_runtime.h>
#include <hip/hip_bf16.h>

#define TB 16384
#define CDIM 512
#define OUTD 512
#define NE 16
#define NE_TOT 17
#define LOSS_SCALE 0.01f
#define BM 256
#define BN 128
#define BK 32
#define NSTEP 16
#define MAX_SCHED 80
#define MAXFLAG 8192
#define MARGIN 1e-3f
#define GATE_BLOCKS (TB / 64)                                  // 256
#define WCONV_BLOCKS ((NE_TOT * OUTD * CDIM / 4 + 255) / 256)  // 4352

typedef __bf16 bf16_t;
typedef bf16_t bf16x8 __attribute__((ext_vector_type(8)));
typedef float f32x4 __attribute__((ext_vector_type(4)));
typedef unsigned short ushort4_t __attribute__((ext_vector_type(4)));
typedef unsigned short ushort8_t __attribute__((ext_vector_type(8)));

__device__ __forceinline__ unsigned short f2bf(float f) {
    unsigned int u = __float_as_uint(f);
    u += 0x7fffu + ((u >> 16) & 1u);   // round-to-nearest-even
    return (unsigned short)(u >> 16);
}
__device__ __forceinline__ float bf2f(unsigned short h) {
    return __uint_as_float((unsigned int)h << 16);
}
// 4-chunk swizzle within a 64B K-tile; depends only on row&15
__device__ __forceinline__ int sw4(int r) { return (r ^ (r >> 2)) & 3; }

__device__ __forceinline__ void async_copy16(void* lds, const void* g) {
    __builtin_amdgcn_global_load_lds(
        (const __attribute__((address_space(1))) unsigned int*)g,
        (__attribute__((address_space(3))) unsigned int*)lds, 16, 0, 0);
}

// ---------------- prep: init small state + assign_w hi/lo bf16 split ----------------
__global__ __launch_bounds__(256) void k_prep(
    const float* __restrict__ aw, unsigned short* __restrict__ awhl,
    int* cnt0, int* cnt1, float* importance, int* nflag, int* wflag)
{
    int t = threadIdx.x;
    if (t < NE) { cnt0[t] = 0; cnt1[t] = 0; importance[t] = 0.f; }
    if (t == 0) { *nflag = 0; *wflag = 0; }
    for (int i = t; i < NE * CDIM; i += 256) {
        float f = aw[i];
        unsigned short h = f2bf(f);
        float r = f - bf2f(h);
        awhl[i] = h;
        awhl[NE * CDIM + i] = f2bf(r);
    }
}

// ---------------- fused front: gate (blocks [0,256)) + wconv (blocks [256, 256+4352)) --
// Bodies are independent: wconv converts pw_w1/bias_w -> wbf (baked sw4 swizzle) and
// sets wflag; gate computes energies via MFMA hi/lo, writes xbf cache, dec, respd,
// flagged tokens, importance partials, and per-rank counts.
__global__ __launch_bounds__(256) void k_front(
    // gate args
    const float* __restrict__ x, const unsigned short* __restrict__ awhl,
    const float* __restrict__ ab, unsigned short* __restrict__ xbf,
    int* __restrict__ dec, float2* __restrict__ respd,
    int* __restrict__ flaglist, int* __restrict__ nflag, float* __restrict__ importance,
    int* __restrict__ cnt0, int* __restrict__ cnt1,
    // wconv args
    const float* __restrict__ pw, const float* __restrict__ bw,
    unsigned short* __restrict__ wbf, int* __restrict__ wflag)
{
    int tid = threadIdx.x;
    if (blockIdx.x >= GATE_BLOCKS) {
        // ---- wconv body ----
        long i = (long)(blockIdx.x - GATE_BLOCKS) * 256 + tid;   // float4 index
        const long NPW = (long)NE * OUTD * CDIM / 4;
        const long NTOT = (long)NE_TOT * OUTD * CDIM / 4;
        if (i >= NTOT) return;
        const float* src = (i < NPW) ? (pw + i * 4) : (bw + (i - NPW) * 4);
        float4 v = *(const float4*)src;
        ushort4_t o;
        o[0] = f2bf(v.x); o[1] = f2bf(v.y); o[2] = f2bf(v.z); o[3] = f2bf(v.w);
        long row = i >> 7;                 // global row (e*512 + out_row)
        int e0 = (int)(i & 127) * 4;       // element offset in row
        int kt = e0 >> 5;                  // which 64B (32-elem) K-tile
        int cc = (e0 >> 3) & 3;            // 16B chunk within tile
        int half = e0 & 7;                 // 0 or 4
        int ccs = cc ^ sw4((int)(row & 15));
        *(ushort4_t*)(wbf + row * CDIM + kt * 32 + ccs * 8 + half) = o;
        if (i >= NPW && (v.x != 0.f || v.y != 0.f || v.z != 0.f || v.w != 0.f))
            atomicOr(wflag, 1);
        return;
    }

    // ---- gate body ----
    __shared__ float imp_s[NE];
    __shared__ int c0_s[NE], c1_s[NE];
    if (tid < NE) { imp_s[tid] = 0.f; c0_s[tid] = 0; c1_s[tid] = 0; }
    __syncthreads();

    int wv = tid >> 6, l = tid & 63;
    int n0 = blockIdx.x * 64 + wv * 16;
    int e = l & 15;          // expert (B row); also A-load token row
    int kg = l >> 4;

    const float* xrow = x + (size_t)(n0 + e) * CDIM + kg * 8;
    unsigned short* xbrow = xbf + (size_t)(n0 + e) * CDIM + kg * 8;
    const unsigned short* whiP = awhl + e * CDIM + kg * 8;
    const unsigned short* wloP = whiP + NE * CDIM;

    f32x4 acc = (f32x4){0.f, 0.f, 0.f, 0.f};
    #pragma unroll 4
    for (int ks = 0; ks < 16; ++ks) {
        float4 v0 = *(const float4*)(xrow + ks * 32);
        float4 v1 = *(const float4*)(xrow + ks * 32 + 4);
        ushort8_t hx, lx;
        #define CVT(idx, f) { unsigned short h_ = f2bf(f); hx[idx] = h_; \
                              float r_ = (f) - bf2f(h_); lx[idx] = f2bf(r_); }
        CVT(0, v0.x) CVT(1, v0.y) CVT(2, v0.z) CVT(3, v0.w)
        CVT(4, v1.x) CVT(5, v1.y) CVT(6, v1.z) CVT(7, v1.w)
        #undef CVT
        *(ushort8_t*)(xbrow + ks * 32) = hx;
        ushort8_t wh8 = *(const ushort8_t*)(whiP + ks * 32);
        ushort8_t wl8 = *(const ushort8_t*)(wloP + ks * 32);
        bf16x8 ah = *(bf16x8*)&hx, al = *(bf16x8*)&lx;
        bf16x8 bh = *(bf16x8*)&wh8, bl = *(bf16x8*)&wl8;
        acc = __builtin_amdgcn_mfma_f32_16x16x32_bf16(al, bh, acc, 0, 0, 0);
        acc = __builtin_amdgcn_mfma_f32_16x16x32_bf16(ah, bl, acc, 0, 0, 0);
        acc = __builtin_amdgcn_mfma_f32_16x16x32_bf16(ah, bh, acc, 0, 0, 0);
    }
    float bias = ab[e];
    f32x4 E;
    #pragma unroll
    for (int q = 0; q < 4; ++q) E[q] = acc[q] + bias;

    f32x4 m1 = E, m2, m3;
    #pragma unroll
    for (int q = 0; q < 4; ++q) { m2[q] = -3.4e38f; m3[q] = -3.4e38f; }
    #pragma unroll
    for (int off = 1; off <= 8; off <<= 1) {
        #pragma unroll
        for (int q = 0; q < 4; ++q) {
            float o1 = __shfl_xor(m1[q], off, 64);
            float o2 = __shfl_xor(m2[q], off, 64);
            float o3 = __shfl_xor(m3[q], off, 64);
            float M1 = fmaxf(m1[q], o1), x1 = fminf(m1[q], o1);
            float h2 = fmaxf(m2[q], o2), l2 = fminf(m2[q], o2);
            float M2 = fmaxf(x1, h2), x2 = fminf(x1, h2);
            float M3 = fmaxf(fmaxf(x2, l2), fmaxf(m3[q], o3));
            m1[q] = M1; m2[q] = M2; m3[q] = M3;
        }
    }
    f32x4 p, z;
    #pragma unroll
    for (int q = 0; q < 4; ++q) p[q] = (E[q] >= m2[q]) ? expf(E[q] - m1[q]) : 0.f;
    z = p;
    #pragma unroll
    for (int off = 1; off <= 8; off <<= 1)
        #pragma unroll
        for (int q = 0; q < 4; ++q) z[q] += __shfl_xor(z[q], off, 64);
    f32x4 resp;
    #pragma unroll
    for (int q = 0; q < 4; ++q) resp[q] = p[q] / z[q];

    int grp = l >> 4;
    int elo_q[4], ehi_q[4];
    float rlo_q[4], rhi_q[4];
    #pragma unroll
    for (int q = 0; q < 4; ++q) {
        unsigned long long mq = __ballot(p[q] > 0.f);
        unsigned int sub = (unsigned int)((mq >> (grp * 16)) & 0xffffULL);
        elo_q[q] = __builtin_ctz(sub);
        ehi_q[q] = 31 - __builtin_clz(sub);
        rlo_q[q] = __shfl(resp[q], grp * 16 + elo_q[q], 64);
        rhi_q[q] = __shfl(resp[q], grp * 16 + ehi_q[q], 64);
    }
    if ((l & 15) == 0) {
        #pragma unroll
        for (int q = 0; q < 4; ++q) {
            int n = n0 + grp * 4 + q;
            dec[n] = elo_q[q] | (ehi_q[q] << 8);
            respd[n] = make_float2(rlo_q[q], rhi_q[q]);
            atomicAdd(&c0_s[elo_q[q]], 1);
            atomicAdd(&c1_s[ehi_q[q]], 1);
            if (m2[q] - m3[q] < MARGIN) {
                int ix = atomicAdd(nflag, 1);
                if (ix < MAXFLAG) flaglist[ix] = n;
            }
        }
    }
    float s = resp[0] + resp[1] + resp[2] + resp[3];
    s += __shfl_xor(s, 16, 64);
    s += __shfl_xor(s, 32, 64);
    if (l < 16) atomicAdd(&imp_s[e], s);
    __syncthreads();
    if (tid < NE) {
        unsafeAtomicAdd(&importance[tid], imp_s[tid]);
        if (c0_s[tid]) atomicAdd(&cnt0[tid], c0_s[tid]);
        if (c1_s[tid]) atomicAdd(&cnt1[tid], c1_s[tid]);
    }
}

// ---------------- fp64 repair for ambiguous tokens (also fixes counts) ----------------
__global__ __launch_bounds__(256) void k_repair(
    const float* __restrict__ x, const float* __restrict__ aw, const float* __restrict__ ab,
    const int* __restrict__ flaglist, const int* __restrict__ nflag,
    int* __restrict__ dec, float2* __restrict__ respd, float* __restrict__ importance,
    int* __restrict__ cnt0, int* __restrict__ cnt1)
{
    __shared__ double part[16][17];
    __shared__ double Ed[16];
    int tid = threadIdx.x;
    int e = tid >> 4, p = tid & 15;
    int nf = *nflag; if (nf > MAXFLAG) nf = MAXFLAG;
    for (int fi = blockIdx.x; fi < nf; fi += gridDim.x) {
        int n = flaglist[fi];
        const float* xp_ = x + (size_t)n * CDIM + p * 32;
        const float* wp = aw + e * CDIM + p * 32;
        double acc = 0.0;
        for (int j = 0; j < 32; ++j) acc = fma((double)xp_[j], (double)wp[j], acc);
        part[e][p] = acc;
        __syncthreads();
        if (tid < 16) {
            double s = (double)ab[tid];
            for (int q = 0; q < 16; ++q) s += part[tid][q];
            Ed[tid] = s;
        }
        __syncthreads();
        if (tid == 0) {
            double m1 = -1e300, m2 = -1e300, m3 = -1e300;
            for (int q = 0; q < 16; ++q) {
                double v = Ed[q];
                if (v > m1) { m3 = m2; m2 = m1; m1 = v; }
                else if (v > m2) { m3 = m2; m2 = v; }
                else if (v > m3) { m3 = v; }
            }
            int elo = -1, ehi = -1;
            for (int q = 0; q < 16; ++q)
                if (Ed[q] >= m2) { if (elo < 0) elo = q; else ehi = q; }
            double plo = exp(Ed[elo] - m1), phi = exp(Ed[ehi] - m1);
            double zz = plo + phi;
            float rlo = (float)(plo / zz), rhi = (float)(phi / zz);
            int od = dec[n]; float2 orr = respd[n];
            int oelo = od & 0xff, oehi = (od >> 8) & 0xff;
            unsafeAtomicAdd(&importance[oelo], -orr.x);
            unsafeAtomicAdd(&importance[oehi], -orr.y);
            unsafeAtomicAdd(&importance[elo], rlo);
            unsafeAtomicAdd(&importance[ehi], rhi);
            if (oelo != elo) { atomicSub(&cnt0[oelo], 1); atomicAdd(&cnt0[elo], 1); }
            if (oehi != ehi) { atomicSub(&cnt1[oehi], 1); atomicAdd(&cnt1[ehi], 1); }
            dec[n] = elo | (ehi << 8);
            respd[n] = make_float2(rlo, rhi);
        }
        __syncthreads();
    }
}

// ---------------- loss + prefix bases + schedules (BM=256 tiles) ----------------
__global__ void k_finish(const float* __restrict__ importance, float* __restrict__ out_loss,
                         const int* __restrict__ cnt0, const int* __restrict__ cnt1,
                         int* __restrict__ fill0, int* __restrict__ fill1,
                         int* __restrict__ end0a, int* __restrict__ end1a,
                         int* __restrict__ sched0, int* __restrict__ sched1,
                         int* __restrict__ sn0, int* __restrict__ sn1) {
    int l = threadIdx.x;
    if (l < 64) {
        float v = (l < NE) ? importance[l] : 0.f;
        float s = v;
        #pragma unroll
        for (int off = 8; off >= 1; off >>= 1) s += __shfl_xor(s, off, 64);
        float mean = s / 16.f;
        float d = (l < NE) ? (v - mean) : 0.f;
        float ss = d * d;
        #pragma unroll
        for (int off = 8; off >= 1; off >>= 1) ss += __shfl_xor(ss, off, 64);
        if (l == 0) {
            float stdv = sqrtf(ss / 15.f);   // ddof=1
            out_loss[0] = LOSS_SCALE * stdv / mean;
        }
    } else if (l == 64) {
        int p = 0, base = 0;
        for (int e = 0; e < NE; ++e) {
            fill0[e] = base;
            end0a[e] = base + cnt0[e];
            int nb = (cnt0[e] + BM - 1) / BM;
            for (int i = 0; i < nb; ++i) sched0[p++] = (e << 20) | (base + i * BM);
            base += cnt0[e];
        }
        *sn0 = p;
    } else if (l == 65) {
        int p = 0, base = 0;
        for (int e = 0; e < NE; ++e) {
            fill1[e] = base;
            end1a[e] = base + cnt1[e];
            int nb = (cnt1[e] + BM - 1) / BM;
            for (int i = 0; i < nb; ++i) sched1[p++] = (e << 20) | (base + i * BM);
            base += cnt1[e];
        }
        *sn1 = p;
    }
}

// ---------------- compacted scatter ----------------
__global__ __launch_bounds__(256) void k_scatter(
    const int* __restrict__ dec, int* __restrict__ fill0, int* __restrict__ fill1,
    int* __restrict__ idx0c, int* __restrict__ idx1c)
{
    __shared__ int l0[NE], l1[NE], b0[NE], b1[NE];
    int tid = threadIdx.x;
    if (tid < NE) { l0[tid] = 0; l1[tid] = 0; }
    __syncthreads();
    int n = blockIdx.x * 256 + tid;
    int d = dec[n];
    int elo = d & 0xff, ehi = (d >> 8) & 0xff;
    int p0 = atomicAdd(&l0[elo], 1);
    int p1 = atomicAdd(&l1[ehi], 1);
    __syncthreads();
    if (tid < NE) {
        b0[tid] = atomicAdd(&fill0[tid], l0[tid]);
        b1[tid] = atomicAdd(&fill1[tid], l1[tid]);
    }
    __syncthreads();
    idx0c[b0[elo] + p0] = n;
    idx1c[b1[ehi] + p1] = n;
}

// ---------------- GEMM: BM=256 BN=128 BK=32, 512 threads (8 waves, 4Mx2N of 64x64),
// dbuf + counted vmcnt(3); ~288 blocks/pass -> all resident (HBM-streaming).
// A gathered from xbf via idxc (per-lane global src; XOR-swizzled chunk);
// B from baked-swizzled wbf (linear src).
// MODE 0: y = w*acc + bias_b; MODE 1: y += w*acc; MODE 2: dense bias expert (y += acc).
template<int MODE>
__global__ __launch_bounds__(512) void k_gemm(
    const unsigned short* __restrict__ xbf, const unsigned short* __restrict__ wbf,
    const int* __restrict__ idxc, const float2* __restrict__ respd,
    const int* __restrict__ sched, const int* __restrict__ sn,
    const int* __restrict__ enda, const int* __restrict__ wflag,
    const float* __restrict__ bias_b, float* __restrict__ y)
{
    int e, m0, end;
    if (MODE == 2) {
        if (*wflag == 0) return;
        e = NE; m0 = blockIdx.x * BM; end = TB;
    } else {
        if ((int)blockIdx.x >= *sn) return;
        int s = sched[blockIdx.x];
        e = s >> 20; m0 = s & 0xFFFFF; end = enda[e];
    }
    int n0 = blockIdx.y * BN;
    int tid = threadIdx.x;
    int wave = tid >> 6, lane = tid & 63;
    int wm = wave >> 1, wn = wave & 1;
    int fr = lane & 15, fq = lane >> 4;

    __shared__ unsigned short As[2][BM * BK];   // 32 KiB
    __shared__ unsigned short Bs[2][BN * BK];   // 16 KiB

    f32x4 acc[4][4];
    #pragma unroll
    for (int m = 0; m < 4; ++m)
        #pragma unroll
        for (int nn = 0; nn < 4; ++nn) acc[m][nn] = (f32x4){0.f, 0.f, 0.f, 0.f};

    // staging: 3 gload_lds per wave per K-tile (A:2, B:1), each = 16 rows x 64B.
    // lane l -> row l>>2, chunk l&3; A global src gathered per-lane + XOR-swizzled
    // chunk (rule #21: linear LDS dest + swizzled source = swizzled read); B baked.
    int rl = lane >> 2, cc = lane & 3;
    const unsigned short* aS[2];
    #pragma unroll
    for (int c = 0; c < 2; ++c) {
        int rloc = wave * 32 + c * 16 + rl;
        int tokr;
        if (MODE == 2) tokr = m0 + rloc;
        else { int rr = m0 + rloc; if (rr >= end) rr = end - 1; tokr = idxc[rr]; }
        aS[c] = xbf + (size_t)tokr * CDIM + (cc ^ sw4(rloc)) * 8;
    }
    const unsigned short* bS =
        wbf + ((size_t)e * OUTD + n0 + wave * 16 + rl) * CDIM + cc * 8;

    auto stage = [&](int buf, int t) {
        async_copy16(&As[buf][(wave * 32) * BK], aS[0] + t * BK);
        async_copy16(&As[buf][(wave * 32 + 16) * BK], aS[1] + t * BK);
        async_copy16(&Bs[buf][(wave * 16) * BK], bS + t * BK);
    };
    auto compute = [&](int cb) {
        bf16x8 af[4], bv[4];
        #pragma unroll
        for (int m = 0; m < 4; ++m) {
            int row = wm * 64 + m * 16 + fr;
            af[m] = *(const bf16x8*)(&As[cb][row * BK + ((fq ^ sw4(fr)) * 8)]);
        }
        #pragma unroll
        for (int nn = 0; nn < 4; ++nn) {
            int row = wn * 64 + nn * 16 + fr;
            bv[nn] = *(const bf16x8*)(&Bs[cb][row * BK + ((fq ^ sw4(fr)) * 8)]);
        }
        #pragma unroll
        for (int m = 0; m < 4; ++m)
            #pragma unroll
            for (int nn = 0; nn < 4; ++nn)
                acc[m][nn] = __builtin_amdgcn_mfma_f32_16x16x32_bf16(af[m], bv[nn], acc[m][nn], 0, 0, 0);
    };

    stage(0, 0); stage(1, 1);              // 2 K-tiles in flight (6 ops/wave)
    #pragma unroll
    for (int t = 0; t < NSTEP; ++t) {
        // T4: counted wait — tile t's 3 ops done, tile t+1's 3 stay in flight.
        if (t < NSTEP - 1) asm volatile("s_waitcnt vmcnt(3)" ::: "memory");
        else               asm volatile("s_waitcnt vmcnt(0)" ::: "memory");
        __builtin_amdgcn_sched_barrier(0);
        __builtin_amdgcn_s_barrier();      // all waves' tile-t loads landed
        asm volatile("" ::: "memory");
        compute(t & 1);
        __builtin_amdgcn_s_barrier();      // all waves done reading buf t&1
        asm volatile("" ::: "memory");
        if (t + 2 < NSTEP) stage(t & 1, t + 2);
    }

    float bb[4];
    if (MODE == 0) {
        #pragma unroll
        for (int nn = 0; nn < 4; ++nn) bb[nn] = bias_b[n0 + wn * 64 + nn * 16 + fr];
    }
    #pragma unroll
    for (int m = 0; m < 4; ++m)
        #pragma unroll
        for (int q = 0; q < 4; ++q) {
            int r = m0 + wm * 64 + m * 16 + fq * 4 + q;
            if (r < end) {
                int tok = (MODE == 2) ? r : idxc[r];
                float w = 1.f;
                if (MODE != 2) {
                    float2 rp = respd[tok];
                    w = (MODE == 0) ? rp.x : rp.y;
                }
                float* yrow = y + (size_t)tok * OUTD + n0 + wn * 64 + fr;
                #pragma unroll
                for (int nn = 0; nn < 4; ++nn) {
                    if (MODE == 0)      yrow[nn * 16] = fmaf(w, acc[m][nn][q], bb[nn]);
                    else if (MODE == 1) yrow[nn * 16] += w * acc[m][nn][q];
                    else                yrow[nn * 16] += acc[m][nn][q];
                }
            }
        }
}

extern "C" void kernel_launch(void* const* d_in, const int* in_sizes, int n_in,
                              void* d_out, int out_size, void* d_ws, size_t ws_size,
                              hipStream_t stream) {
    const float* x        = (const float*)d_in[0];
    const float* assign_w = (const float*)d_in[1];
    const float* assign_b = (const float*)d_in[2];
    const float* pw_w1    = (const float*)d_in[3];
    const float* bias_w   = (const float*)d_in[4];
    const float* bias_b   = (const float*)d_in[5];
    float* y    = (float*)d_out;                 // [TB*OUTD]
    float* loss = y + (size_t)TB * OUTD;         // [1]

    char* ws = (char*)d_ws;
    unsigned short* wbf  = (unsigned short*)(ws);                 //  8,912,896 B
    unsigned short* xbf  = (unsigned short*)(ws + 8912896);       // 16,777,216 B
    int*    idx0c     = (int*)   (ws + 25690112);                 //     65,536 B
    int*    idx1c     = (int*)   (ws + 25755648);                 //     65,536 B
    int*    dec       = (int*)   (ws + 25821184);                 //     65,536 B
    float2* respd     = (float2*)(ws + 25886720);                 //    131,072 B
    int*    flaglist  = (int*)   (ws + 26017792);                 //     32,768 B
    unsigned short* awhl = (unsigned short*)(ws + 26050560);      //     32,768 B
    char*   misc      = ws + 26083328;
    int*    cnt0      = (int*)   (misc + 0);
    int*    cnt1      = (int*)   (misc + 64);
    int*    fill0     = (int*)   (misc + 128);
    int*    fill1     = (int*)   (misc + 192);
    int*    end0a     = (int*)   (misc + 256);
    int*    end1a     = (int*)   (misc + 320);
    float*  importance= (float*) (misc + 384);
    int*    nflag     = (int*)   (misc + 448);
    int*    wflag     = (int*)   (misc + 452);
    int*    sn0       = (int*)   (misc + 456);
    int*    sn1       = (int*)   (misc + 460);
    int*    sched0    = (int*)   (misc + 512);                    // 80*4
    int*    sched1    = (int*)   (misc + 832);                    // 80*4

    k_prep<<<1, 256, 0, stream>>>(assign_w, awhl, cnt0, cnt1, importance, nflag, wflag);
    k_front<<<GATE_BLOCKS + WCONV_BLOCKS, 256, 0, stream>>>(
        x, awhl, assign_b, xbf, dec, respd, flaglist, nflag, importance, cnt0, cnt1,
        pw_w1, bias_w, wbf, wflag);
    k_repair<<<32, 256, 0, stream>>>(x, assign_w, assign_b, flaglist, nflag,
                                     dec, respd, importance, cnt0, cnt1);
    k_finish<<<1, 128, 0, stream>>>(importance, loss, cnt0, cnt1, fill0, fill1,
                                    end0a, end1a, sched0, sched1, sn0, sn1);
    k_scatter<<<TB / 256, 256, 0, stream>>>(dec, fill0, fill1, idx0c, idx1c);
    k_gemm<0><<<dim3(MAX_SCHED, OUTD / BN), 512, 0, stream>>>(
        xbf, wbf, idx0c, respd, sched0, sn0, end0a, wflag, bias_b, y);
    k_gemm<1><<<dim3(MAX_SCHED, OUTD / BN), 512, 0, stream>>>(
        xbf, wbf, idx1c, respd, sched1, sn1, end1a, wflag, bias_b, y);
    k_gemm<2><<<dim3(TB / BM, OUTD / BN), 512, 0, stream>>>(
        xbf, wbf, idx1c, respd, sched1, sn1, end1a, wflag, bias_b, y);
}